// Round 10
// baseline (9010.225 us; speedup 1.0000x reference)
//
#include <hip/hip_runtime.h>
#include <hip/hip_bf16.h>
#include <hip/hip_fp16.h>

// Problem constants: N=100000, F=128, O=128, S=4, B=2, E=3200000
#define NN 100000
#define FF 128
#define OO 128
#define SS 4
#define BBASES 2
#define EE 3200000
#define TOTE (SS * EE)               // 12.8M edges total
#define RR 16                        // dest rows per bin (N % 16 == 0)
#define RSHIFT 4
#define NBINS ((NN + RR - 1) / RR)   // 6250
#define RBLOCKS 512                  // blocks for hist/reorder

// clang vector types usable with __builtin_nontemporal_* (HIP uint2/float4 are not)
typedef unsigned int uintx2 __attribute__((ext_vector_type(2)));
typedef float floatx4 __attribute__((ext_vector_type(4)));

// ===========================================================================
// out[n] = tanh( sum_b (sum_s Wc[s,b] * G_s[n]) @ W_b ),
//   G_s[n] = sum_{e in s: row_e=n} val_e * feat[col_e]
// Empirical law from R2-R9: fused time = (#waitcnt-drain batches) x ~10.4ns,
// independent of bytes/atomics per batch. So: 64-edge batches (4x R9 depth).
// Per batch: ONE 512B record load (lane=record, readlane broadcast), 64
// independent fp16 gathers held live (sched_barrier pin), branch-free
// consume (2 ds_adds/edge, wave-uniform scalar mask for the padded tail).
// ===========================================================================

__global__ __launch_bounds__(256) void hist_kernel(const int* __restrict__ rows,
                                                   unsigned int* __restrict__ hist) {
  __shared__ unsigned int lh[NBINS];
  for (int i = threadIdx.x; i < NBINS; i += 256) lh[i] = 0;
  __syncthreads();
  const int stride = gridDim.x * 256;
  for (int i = blockIdx.x * 256 + threadIdx.x; i < TOTE; i += stride)
    atomicAdd(&lh[((unsigned)rows[i]) >> RSHIFT], 1u);
  __syncthreads();
  for (int i = threadIdx.x; i < NBINS; i += 256) {
    unsigned int c = lh[i];
    if (c) atomicAdd(&hist[i], c);
  }
}

__global__ __launch_bounds__(256) void scan_kernel(const unsigned int* __restrict__ hist,
                                                   unsigned int* __restrict__ bin_start,
                                                   unsigned int* __restrict__ cursor) {
  __shared__ unsigned int sums[256];
  const int C = (NBINS + 255) / 256;  // 25
  const int t = threadIdx.x;
  unsigned int s = 0;
  for (int j = 0; j < C; ++j) {
    int i = t * C + j;
    if (i < NBINS) s += hist[i];
  }
  sums[t] = s;
  __syncthreads();
  for (int off = 1; off < 256; off <<= 1) {
    unsigned int v = (t >= off) ? sums[t - off] : 0u;
    __syncthreads();
    sums[t] += v;
    __syncthreads();
  }
  unsigned int base = (t == 0) ? 0u : sums[t - 1];
  for (int j = 0; j < C; ++j) {
    int i = t * C + j;
    if (i < NBINS) {
      unsigned int h = hist[i];
      bin_start[i] = base;
      cursor[i] = base;
      base += h;
    }
  }
  if (t == 255) bin_start[NBINS] = base;  // == TOTE
}

__global__ __launch_bounds__(256) void reorder_kernel(
    const int* __restrict__ rows, const int* __restrict__ cols,
    const float* __restrict__ vals, unsigned int* __restrict__ cursor,
    uintx2* __restrict__ sorted) {
  __shared__ unsigned int lcnt[NBINS];
  __shared__ unsigned int lbase[NBINS];
  const int C = (TOTE + RBLOCKS - 1) / RBLOCKS;  // 25000
  const int start = blockIdx.x * C;
  const int end = min(start + C, TOTE);
  for (int i = threadIdx.x; i < NBINS; i += 256) lcnt[i] = 0;
  __syncthreads();
  for (int i = start + threadIdx.x; i < end; i += 256)
    atomicAdd(&lcnt[((unsigned)rows[i]) >> RSHIFT], 1u);
  __syncthreads();
  for (int i = threadIdx.x; i < NBINS; i += 256) {
    unsigned int c = lcnt[i];
    if (c) lbase[i] = atomicAdd(&cursor[i], c);
    lcnt[i] = 0;
  }
  __syncthreads();
  for (int i = start + threadIdx.x; i < end; i += 256) {
    unsigned int r = (unsigned)rows[i];
    int bin = r >> RSHIFT;
    unsigned int p = lbase[bin] + atomicAdd(&lcnt[bin], 1u);
    int s = i / EE;  // support id
    uintx2 rec;
    // bits [16:0]=col, [20:17]=row-in-bin, [22:21]=support
    rec.x = ((unsigned)cols[i]) | ((r & (RR - 1u)) << 17) | (((unsigned)s) << 21);
    rec.y = __float_as_uint(vals[i]);
    __builtin_nontemporal_store(rec, &sorted[p]);
  }
}

// ---- fp16 cast of feat: fb[i] packs elements 2i,2i+1 as half2 (RNE) -------
__global__ __launch_bounds__(256) void cast_kernel(const float* __restrict__ f,
                                                   unsigned int* __restrict__ fb) {
  int i = blockIdx.x * 256 + threadIdx.x;  // over N*F/2 = 6.4M pairs
  float2 a = reinterpret_cast<const float2*>(f)[i];
  __half2 h = __floats2half2_rn(a.x, a.y);
  fb[i] = *reinterpret_cast<unsigned int*>(&h);
}

// ---- fused: 64-deep batched accumulate + Wc-fold GEMM + tanh --------------
// Lane l holds feature elements 2l, 2l+1. G slot map: elem 2h+p -> p*64+h.
// MODE: 0 = f32 gathers (16-deep), 1 = fp16 gathers (64-deep).
template <int MODE>
__global__ __launch_bounds__(256, 3) void fused_kernel(
    const float* __restrict__ feat, const unsigned int* __restrict__ featb,
    const float* __restrict__ W, const float* __restrict__ Wc,
    const uintx2* __restrict__ sorted, const unsigned int* __restrict__ bin_start,
    float* __restrict__ out) {
  __shared__ float G[SS * RR * FF];  // 4*16*128*4B = 32 KB, G_s contiguous
  const int tid = threadIdx.x;
  const int lane = tid & 63;
  const int wid = tid >> 6;

  float4* gz = (float4*)G;
#pragma unroll
  for (int i = 0; i < (SS * RR * FF / 4) / 256; ++i)  // 8 iters
    gz[tid + i * 256] = make_float4(0.f, 0.f, 0.f, 0.f);
  __syncthreads();

  const int bin = blockIdx.x;
  const unsigned int e0 = bin_start[bin];
  const unsigned int e1 = bin_start[bin + 1];
  const int L = (int)(e1 - e0);
  constexpr unsigned BT = (MODE == 1) ? 64u : 16u;
  const unsigned int chunk =
      (((unsigned)(L + 3) >> 2) + (BT - 1u)) & ~(BT - 1u);
  unsigned int e = e0 + (unsigned)wid * chunk;
  unsigned int ew = e + chunk;
  if (ew > e1) ew = e1;

  if constexpr (MODE == 1) {
    // 64 edges/batch. Record load: lane reads record e+lane (512B, 1 load).
    // Padded lanes clamp to a valid record in this bin; consume is masked by
    // a wave-uniform scalar test (no divergence, no serial tail).
    const unsigned int nb = (e < ew) ? ((ew - e + 63u) >> 6) : 0u;
    for (unsigned int b = 0; b < nb; ++b) {
      const unsigned int base = e + (b << 6);
      unsigned int idx = base + (unsigned)lane;
      if (idx >= e1) idx = e1 - 1u;  // bin nonempty here
      uintx2 RA = sorted[idx];
      unsigned int x[64];
#pragma unroll
      for (int j = 0; j < 64; ++j) {
        unsigned int c =
            ((unsigned)__builtin_amdgcn_readlane((int)RA.x, j)) & 0x1FFFFu;
        x[j] = featb[((size_t)c << 6) + lane];  // 4B = elems 2l,2l+1 (half2)
      }
      __builtin_amdgcn_sched_barrier(0);  // all 64 gathers issued & held live
#pragma unroll
      for (int j = 0; j < 64; ++j) {
        if (base + j < ew) {  // wave-uniform scalar branch
          unsigned int rx = (unsigned)__builtin_amdgcn_readlane((int)RA.x, j);
          float v = __uint_as_float(
              (unsigned)__builtin_amdgcn_readlane((int)RA.y, j));
          int gb = (int)(((rx >> 17) & 63u) << 7);  // (s*16+ro)*128
          float2 xv = __half22float2(*reinterpret_cast<__half2*>(&x[j]));
          atomicAdd(&G[gb + lane], v * xv.x);
          atomicAdd(&G[gb + 64 + lane], v * xv.y);
        }
      }
    }
  } else {
    // f32 fallback: 16-deep batches + serial tail (R9-proven)
    uintx2 RA;
    if (e + 16 <= ew) RA = sorted[e + (lane & 15)];
    while (e + 16 <= ew) {
      unsigned int np = e + 16;
      unsigned int pidx = np + (lane & 15);
      if (pidx >= e1) pidx = e1 - 1;
      uintx2 RB = sorted[pidx];
      float2 x[16];
#pragma unroll
      for (int j = 0; j < 16; ++j) {
        unsigned int c =
            ((unsigned)__builtin_amdgcn_readlane((int)RA.x, j)) & 0x1FFFFu;
        x[j] = *reinterpret_cast<const float2*>(
            &feat[((size_t)c << 7) + (lane << 1)]);
      }
      __builtin_amdgcn_sched_barrier(0);
#pragma unroll
      for (int j = 0; j < 16; ++j) {
        unsigned int rx = (unsigned)__builtin_amdgcn_readlane((int)RA.x, j);
        float v = __uint_as_float(
            (unsigned)__builtin_amdgcn_readlane((int)RA.y, j));
        int gb = (int)(((rx >> 17) & 63u) << 7);
        atomicAdd(&G[gb + lane], v * x[j].x);
        atomicAdd(&G[gb + 64 + lane], v * x[j].y);
      }
      RA = RB;
      e = np;
    }
    while (e < ew) {
      uintx2 R1 = sorted[e];
      unsigned int rx = R1.x;
      float v = __uint_as_float(R1.y);
      unsigned int c = rx & 0x1FFFFu;
      int gb = (int)(((rx >> 17) & 63u) << 7);
      float2 xv = *reinterpret_cast<const float2*>(
          &feat[((size_t)c << 7) + (lane << 1)]);
      atomicAdd(&G[gb + lane], v * xv.x);
      atomicAdd(&G[gb + 64 + lane], v * xv.y);
      ++e;
    }
  }
  __syncthreads();

  // ---- epilogue: fold supports with Wc, GEMM vs W0,W1, tanh, store ----
  // element k=2h+p lives at slot p*64+h of each G_s row. (validated R6/R9)
  const float cb0[4] = {Wc[0], Wc[2], Wc[4], Wc[6]};
  const float cb1[4] = {Wc[1], Wc[3], Wc[5], Wc[7]};
  const int tx = tid & 31;  // output cols tx*4 .. tx*4+3
  const int ty = tid >> 5;  // 0..7 -> rows 2ty, 2ty+1
  float acc[2][4];
#pragma unroll
  for (int r = 0; r < 2; ++r)
#pragma unroll
    for (int c = 0; c < 4; ++c) acc[r][c] = 0.f;

  const float* W0 = W;
  const float* W1 = W + FF * OO;
#pragma unroll
  for (int p = 0; p < 2; ++p) {
    for (int h0 = 0; h0 < 64; h0 += 4) {
      float4 as_[2][4];
#pragma unroll
      for (int r = 0; r < 2; ++r)
#pragma unroll
        for (int s = 0; s < 4; ++s)
          as_[r][s] = *reinterpret_cast<const float4*>(
              &G[s * (RR * FF) + ((ty * 2 + r) << 7) + p * 64 + h0]);
#pragma unroll
      for (int i = 0; i < 4; ++i) {
        int k = 2 * (h0 + i) + p;
        float4 b0 = *reinterpret_cast<const float4*>(&W0[k * OO + tx * 4]);
        float4 b1 = *reinterpret_cast<const float4*>(&W1[k * OO + tx * 4]);
#pragma unroll
        for (int r = 0; r < 2; ++r) {
          float g0 = 0.f, g1 = 0.f;
#pragma unroll
          for (int s = 0; s < 4; ++s) {
            float a = reinterpret_cast<const float*>(&as_[r][s])[i];
            g0 += cb0[s] * a;
            g1 += cb1[s] * a;
          }
          acc[r][0] += g0 * b0.x + g1 * b1.x;
          acc[r][1] += g0 * b0.y + g1 * b1.y;
          acc[r][2] += g0 * b0.z + g1 * b1.z;
          acc[r][3] += g0 * b0.w + g1 * b1.w;
        }
      }
    }
  }
#pragma unroll
  for (int r = 0; r < 2; ++r) {
    int row = bin * RR + ty * 2 + r;  // N divisible by 16
    floatx4 o;
    o.x = tanhf(acc[r][0]);
    o.y = tanhf(acc[r][1]);
    o.z = tanhf(acc[r][2]);
    o.w = tanhf(acc[r][3]);
    __builtin_nontemporal_store(o, (floatx4*)&out[(size_t)row * OO + tx * 4]);
  }
}

// ===========================================================================
// FALLBACK PATH (round-1, proven): used only if ws_size is too small
// ===========================================================================
__global__ void compute_V_kernel(const float* __restrict__ W,
                                 const float* __restrict__ Wc,
                                 float* __restrict__ V) {
  int i = blockIdx.x * blockDim.x + threadIdx.x;
  int s = i >> 14;
  int fo = i & 16383;
  V[i] = Wc[s * BBASES + 0] * W[fo] + Wc[s * BBASES + 1] * W[16384 + fo];
}

__global__ __launch_bounds__(256) void scatter_kernel(
    const float* __restrict__ feat, const int* __restrict__ rows,
    const int* __restrict__ cols, const float* __restrict__ vals,
    float* __restrict__ agg) {
  int t = blockIdx.x * blockDim.x + threadIdx.x;
  int e = t >> 5;
  int q = t & 31;
  if (e >= EE) return;
  int r = rows[e];
  int c = cols[e];
  float v = vals[e];
  const float4 x = *reinterpret_cast<const float4*>(&feat[(size_t)c * FF + q * 4]);
  float* dst = &agg[(size_t)r * FF + q * 4];
  unsafeAtomicAdd(dst + 0, v * x.x);
  unsafeAtomicAdd(dst + 1, v * x.y);
  unsafeAtomicAdd(dst + 2, v * x.z);
  unsafeAtomicAdd(dst + 3, v * x.w);
}

__global__ __launch_bounds__(256) void gemm_acc_kernel(
    const float* __restrict__ A, const float* __restrict__ Bv,
    float* __restrict__ C) {
  __shared__ float As[16][64];
  __shared__ float Bs[16][128];
  const int tid = threadIdx.x;
  const int bm0 = blockIdx.x * 64;
  const int tx = tid & 31;
  const int ty = tid >> 5;
  float acc[8][4];
#pragma unroll
  for (int r = 0; r < 8; ++r)
#pragma unroll
    for (int c = 0; c < 4; ++c) acc[r][c] = 0.0f;
  const int ar = tid >> 2;
  const int akq = tid & 3;
  for (int k0 = 0; k0 < FF; k0 += 16) {
    {
      int row = bm0 + ar;
      float4 av = make_float4(0.f, 0.f, 0.f, 0.f);
      if (row < NN)
        av = *reinterpret_cast<const float4*>(&A[(size_t)row * FF + k0 + akq * 4]);
      As[akq * 4 + 0][ar] = av.x;
      As[akq * 4 + 1][ar] = av.y;
      As[akq * 4 + 2][ar] = av.z;
      As[akq * 4 + 3][ar] = av.w;
    }
#pragma unroll
    for (int i = 0; i < 2; ++i) {
      int v = tid + i * 256;
      int kk = v >> 5;
      int cq = v & 31;
      *reinterpret_cast<float4*>(&Bs[kk][cq * 4]) =
          *reinterpret_cast<const float4*>(&Bv[(k0 + kk) * OO + cq * 4]);
    }
    __syncthreads();
#pragma unroll
    for (int kk = 0; kk < 16; ++kk) {
      float4 b = *reinterpret_cast<const float4*>(&Bs[kk][tx * 4]);
#pragma unroll
      for (int r = 0; r < 8; ++r) {
        float a = As[kk][ty * 8 + r];
        acc[r][0] += a * b.x;
        acc[r][1] += a * b.y;
        acc[r][2] += a * b.z;
        acc[r][3] += a * b.w;
      }
    }
    __syncthreads();
  }
#pragma unroll
  for (int r = 0; r < 8; ++r) {
    int row = bm0 + ty * 8 + r;
    if (row < NN) {
      float4* cp = reinterpret_cast<float4*>(&C[(size_t)row * OO + tx * 4]);
      float4 c = *cp;
      c.x += acc[r][0];
      c.y += acc[r][1];
      c.z += acc[r][2];
      c.w += acc[r][3];
      *cp = c;
    }
  }
}

__global__ __launch_bounds__(256) void tanh_kernel(float* __restrict__ out) {
  int i = blockIdx.x * blockDim.x + threadIdx.x;
  float4* p = reinterpret_cast<float4*>(out) + i;
  float4 v = *p;
  v.x = tanhf(v.x);
  v.y = tanhf(v.y);
  v.z = tanhf(v.z);
  v.w = tanhf(v.w);
  *p = v;
}

// ===========================================================================
extern "C" void kernel_launch(void* const* d_in, const int* in_sizes, int n_in,
                              void* d_out, int out_size, void* d_ws,
                              size_t ws_size, hipStream_t stream) {
  const float* feat = (const float*)d_in[0];   // [N, F]
  const float* W = (const float*)d_in[1];      // [B, F, O]
  const float* Wc = (const float*)d_in[2];     // [S, B]
  const int* erows = (const int*)d_in[3];      // [S, E]
  const int* ecols = (const int*)d_in[4];      // [S, E]
  const float* evals = (const float*)d_in[5];  // [S, E]
  float* out = (float*)d_out;                  // [N, O] f32

  unsigned char* ws = (unsigned char*)d_ws;
  unsigned int* hist = (unsigned int*)ws;                 // NBINS
  unsigned int* bin_start = hist + NBINS;                 // NBINS+1
  unsigned int* cursor = bin_start + NBINS + 1;           // NBINS
  size_t sorted_off = (((size_t)(3 * NBINS + 1) * 4) + 255) & ~(size_t)255;
  uintx2* sorted = (uintx2*)(ws + sorted_off);            // TOTE * 8B
  size_t featb_off = sorted_off + (size_t)TOTE * 8;
  unsigned int* featb = (unsigned int*)(ws + featb_off);  // N*F/2 uints (25.6MB)
  size_t needed_f32 = featb_off;
  size_t needed_f16 = featb_off + (size_t)NN * FF * 2;

  if (ws_size >= needed_f32) {
    hipMemsetAsync(hist, 0, (size_t)NBINS * 4, stream);
    hist_kernel<<<RBLOCKS, 256, 0, stream>>>(erows, hist);
    scan_kernel<<<1, 256, 0, stream>>>(hist, bin_start, cursor);
    reorder_kernel<<<RBLOCKS, 256, 0, stream>>>(erows, ecols, evals, cursor, sorted);
    if (ws_size >= needed_f16) {
      cast_kernel<<<(NN * FF / 2) / 256, 256, 0, stream>>>(feat, featb);
      fused_kernel<1><<<NBINS, 256, 0, stream>>>(feat, featb, W, Wc, sorted,
                                                 bin_start, out);
    } else {
      fused_kernel<0><<<NBINS, 256, 0, stream>>>(feat, featb, W, Wc, sorted,
                                                 bin_start, out);
    }
  } else {
    float* V = (float*)d_ws;
    float* agg = V + (size_t)SS * FF * OO;
    compute_V_kernel<<<(SS * FF * OO) / 256, 256, 0, stream>>>(W, Wc, V);
    hipMemsetAsync(out, 0, (size_t)NN * OO * sizeof(float), stream);
    for (int s = 0; s < SS; ++s) {
      hipMemsetAsync(agg, 0, (size_t)NN * FF * sizeof(float), stream);
      scatter_kernel<<<(EE * 32) / 256, 256, 0, stream>>>(
          feat, erows + (size_t)s * EE, ecols + (size_t)s * EE,
          evals + (size_t)s * EE, agg);
      gemm_acc_kernel<<<(NN + 63) / 64, 256, 0, stream>>>(
          agg, V + (size_t)s * FF * OO, out);
    }
    tanh_kernel<<<(NN * OO / 4) / 256, 256, 0, stream>>>(out);
  }
}

// Round 11
// 2385.080 us; speedup vs baseline: 3.7777x; 3.7777x over previous
//
#include <hip/hip_runtime.h>
#include <hip/hip_bf16.h>
#include <hip/hip_fp16.h>

// Problem constants: N=100000, F=128, O=128, S=4, B=2, E=3200000
#define NN 100000
#define FF 128
#define OO 128
#define SS 4
#define BBASES 2
#define EE 3200000
#define TOTE (SS * EE)  // 12.8M edges total

typedef unsigned int uintx2 __attribute__((ext_vector_type(2)));
typedef float floatx4 __attribute__((ext_vector_type(4)));

// ===========================================================================
// out[n] = tanh( G0[n] @ W0 + G1[n] @ W1 ),
//   G_b[n] = sum_s Wc[s,b] * sum_{e in s: row_e=n} val_e * feat[col_e]
// PULL design (R11): CSR by dest row, then one thread owns (row, 8 features)
// and gathers its row's edges in a dense register-accumulate loop — no LDS
// ops / atomics / readlane in the hot loop (the shapes hipcc refuses to
// pipeline, proven R5/R6/R9/R10). GEMM+tanh epilogue fused per 16-row block.
// ===========================================================================

// ---- per-row histogram (rs[r] = count) ------------------------------------
__global__ __launch_bounds__(256) void hist_row_kernel(
    const int* __restrict__ rows, unsigned int* __restrict__ rs) {
  const int stride = gridDim.x * 256;
  for (int i = blockIdx.x * 256 + threadIdx.x; i < TOTE; i += stride)
    atomicAdd(&rs[rows[i]], 1u);
}

// ---- exclusive scan over NN rows, single block of 1024 --------------------
__global__ __launch_bounds__(1024) void scan_row_kernel(
    unsigned int* __restrict__ rs) {
  __shared__ unsigned int sums[1024];
  const int t = threadIdx.x;
  const int C = (NN + 1023) / 1024;  // 98
  unsigned int s = 0;
  for (int j = 0; j < C; ++j) {
    int i = t * C + j;
    if (i < NN) s += rs[i];
  }
  sums[t] = s;
  __syncthreads();
  for (int off = 1; off < 1024; off <<= 1) {
    unsigned int v = (t >= off) ? sums[t - off] : 0u;
    __syncthreads();
    sums[t] += v;
    __syncthreads();
  }
  unsigned int base = (t == 0) ? 0u : sums[t - 1];
  for (int j = 0; j < C; ++j) {
    int i = t * C + j;
    if (i < NN) {
      unsigned int h = rs[i];
      rs[i] = base;  // exclusive start
      base += h;
    }
  }
}

// ---- reorder edges into row-CSR; rs[r] becomes END of row r ---------------
__global__ __launch_bounds__(256) void reorder_row_kernel(
    const int* __restrict__ rows, const int* __restrict__ cols,
    const float* __restrict__ vals, unsigned int* __restrict__ rs,
    uintx2* __restrict__ recs) {
  const int stride = gridDim.x * 256;
  for (int i = blockIdx.x * 256 + threadIdx.x; i < TOTE; i += stride) {
    int r = rows[i];
    unsigned int p = atomicAdd(&rs[r], 1u);
    unsigned int s = (unsigned)(i / EE);  // support id (magic-mul)
    uintx2 rec;
    rec.x = ((unsigned)cols[i]) | (s << 17);  // col:17 bits, s:2 bits
    rec.y = __float_as_uint(vals[i]);
    __builtin_nontemporal_store(rec, &recs[p]);
  }
}

// ---- fp16 cast of feat: fb[i] packs elements 2i,2i+1 as half2 (RNE) -------
__global__ __launch_bounds__(256) void cast_kernel(const float* __restrict__ f,
                                                   unsigned int* __restrict__ fb) {
  int i = blockIdx.x * 256 + threadIdx.x;  // over N*F/2 = 6.4M pairs
  float2 a = reinterpret_cast<const float2*>(f)[i];
  __half2 h = __floats2half2_rn(a.x, a.y);
  fb[i] = *reinterpret_cast<unsigned int*>(&h);
}

// ---- pull + fused GEMM + tanh ---------------------------------------------
// Block = 16 rows x 16 threads/row. Thread (nl, q) accumulates features
// 8q..8q+7 of G0,G1 for row nl in registers; LDS G[16][256]; epilogue GEMM
// vs stacked [W0;W1] (K=256) + tanh. MODE: 1 = fp16 featb, 0 = f32 feat.
template <int MODE>
__global__ __launch_bounds__(256, 6) void pull_fused_kernel(
    const float* __restrict__ feat, const unsigned int* __restrict__ featb,
    const float* __restrict__ W, const float* __restrict__ Wc,
    const uintx2* __restrict__ recs, const unsigned int* __restrict__ rs,
    float* __restrict__ out) {
  __shared__ float G[16][2 * FF];  // 16 KB
  const int tid = threadIdx.x;
  const int nl = tid >> 4;   // 0..15 row within block
  const int q = tid & 15;    // feature chunk: elems 8q..8q+7
  const int n = blockIdx.x * 16 + nl;

  // after reorder, rs[r] = end of row r; start = rs[r-1] (or 0)
  const unsigned int e1 = rs[n];
  const unsigned int e0 = (n == 0) ? 0u : rs[n - 1];

  const float c00 = Wc[0], c01 = Wc[1], c10 = Wc[2], c11 = Wc[3];
  const float c20 = Wc[4], c21 = Wc[5], c30 = Wc[6], c31 = Wc[7];

  float a0[8], a1[8];
#pragma unroll
  for (int k = 0; k < 8; ++k) {
    a0[k] = 0.f;
    a1[k] = 0.f;
  }

  for (unsigned int e = e0; e < e1; ++e) {
    uintx2 rec = recs[e];  // 8B, shared by the 16 threads of this row
    unsigned int c = rec.x & 0x1FFFFu;
    unsigned int s = rec.x >> 17;
    float v = __uint_as_float(rec.y);
    float w0 = (s == 0) ? c00 : (s == 1) ? c10 : (s == 2) ? c20 : c30;
    float w1 = (s == 0) ? c01 : (s == 1) ? c11 : (s == 2) ? c21 : c31;
    float v0 = v * w0, v1 = v * w1;
    if constexpr (MODE == 1) {
      uint4 xv = *reinterpret_cast<const uint4*>(&featb[((size_t)c << 6) + (q << 2)]);
      const __half2* hp = reinterpret_cast<const __half2*>(&xv);
#pragma unroll
      for (int h = 0; h < 4; ++h) {
        float2 f = __half22float2(hp[h]);
        a0[2 * h] += v0 * f.x;
        a0[2 * h + 1] += v0 * f.y;
        a1[2 * h] += v1 * f.x;
        a1[2 * h + 1] += v1 * f.y;
      }
    } else {
      float4 xa = *reinterpret_cast<const float4*>(&feat[((size_t)c << 7) + (q << 3)]);
      float4 xb = *reinterpret_cast<const float4*>(&feat[((size_t)c << 7) + (q << 3) + 4]);
      a0[0] += v0 * xa.x; a0[1] += v0 * xa.y; a0[2] += v0 * xa.z; a0[3] += v0 * xa.w;
      a0[4] += v0 * xb.x; a0[5] += v0 * xb.y; a0[6] += v0 * xb.z; a0[7] += v0 * xb.w;
      a1[0] += v1 * xa.x; a1[1] += v1 * xa.y; a1[2] += v1 * xa.z; a1[3] += v1 * xa.w;
      a1[4] += v1 * xb.x; a1[5] += v1 * xb.y; a1[6] += v1 * xb.z; a1[7] += v1 * xb.w;
    }
  }

#pragma unroll
  for (int k = 0; k < 8; ++k) {
    G[nl][q * 8 + k] = a0[k];
    G[nl][FF + q * 8 + k] = a1[k];
  }
  __syncthreads();

  // ---- GEMM epilogue: out[row][o] = tanh(sum_{k<256} G[r][k]*Wcat[k][o]) ----
  // W is [B][F][O] contiguous = stacked [256][128]; G[r][k<128]=G0, rest G1.
  const int tx = tid & 31;  // cols tx*4..tx*4+3
  const int ty = tid >> 5;  // 0..7 -> rows 2ty, 2ty+1
  float acc[2][4];
#pragma unroll
  for (int r = 0; r < 2; ++r)
#pragma unroll
    for (int c = 0; c < 4; ++c) acc[r][c] = 0.f;

  for (int k = 0; k < 2 * FF; ++k) {
    float4 bv = *reinterpret_cast<const float4*>(&W[k * OO + tx * 4]);
#pragma unroll
    for (int r = 0; r < 2; ++r) {
      float a = G[ty * 2 + r][k];  // broadcast within half-wave
      acc[r][0] += a * bv.x;
      acc[r][1] += a * bv.y;
      acc[r][2] += a * bv.z;
      acc[r][3] += a * bv.w;
    }
  }
#pragma unroll
  for (int r = 0; r < 2; ++r) {
    int row = blockIdx.x * 16 + ty * 2 + r;  // N divisible by 16
    floatx4 o;
    o.x = tanhf(acc[r][0]);
    o.y = tanhf(acc[r][1]);
    o.z = tanhf(acc[r][2]);
    o.w = tanhf(acc[r][3]);
    __builtin_nontemporal_store(o, (floatx4*)&out[(size_t)row * OO + tx * 4]);
  }
}

// ===========================================================================
// FALLBACK PATH (round-1, proven): used only if ws_size is too small
// ===========================================================================
__global__ void compute_V_kernel(const float* __restrict__ W,
                                 const float* __restrict__ Wc,
                                 float* __restrict__ V) {
  int i = blockIdx.x * blockDim.x + threadIdx.x;
  int s = i >> 14;
  int fo = i & 16383;
  V[i] = Wc[s * BBASES + 0] * W[fo] + Wc[s * BBASES + 1] * W[16384 + fo];
}

__global__ __launch_bounds__(256) void scatter_kernel(
    const float* __restrict__ feat, const int* __restrict__ rows,
    const int* __restrict__ cols, const float* __restrict__ vals,
    float* __restrict__ agg) {
  int t = blockIdx.x * blockDim.x + threadIdx.x;
  int e = t >> 5;
  int qq = t & 31;
  if (e >= EE) return;
  int r = rows[e];
  int c = cols[e];
  float v = vals[e];
  const float4 x = *reinterpret_cast<const float4*>(&feat[(size_t)c * FF + qq * 4]);
  float* dst = &agg[(size_t)r * FF + qq * 4];
  unsafeAtomicAdd(dst + 0, v * x.x);
  unsafeAtomicAdd(dst + 1, v * x.y);
  unsafeAtomicAdd(dst + 2, v * x.z);
  unsafeAtomicAdd(dst + 3, v * x.w);
}

__global__ __launch_bounds__(256) void gemm_acc_kernel(
    const float* __restrict__ A, const float* __restrict__ Bv,
    float* __restrict__ C) {
  __shared__ float As[16][64];
  __shared__ float Bs[16][128];
  const int tid = threadIdx.x;
  const int bm0 = blockIdx.x * 64;
  const int tx = tid & 31;
  const int ty = tid >> 5;
  float acc[8][4];
#pragma unroll
  for (int r = 0; r < 8; ++r)
#pragma unroll
    for (int c = 0; c < 4; ++c) acc[r][c] = 0.0f;
  const int ar = tid >> 2;
  const int akq = tid & 3;
  for (int k0 = 0; k0 < FF; k0 += 16) {
    {
      int row = bm0 + ar;
      float4 av = make_float4(0.f, 0.f, 0.f, 0.f);
      if (row < NN)
        av = *reinterpret_cast<const float4*>(&A[(size_t)row * FF + k0 + akq * 4]);
      As[akq * 4 + 0][ar] = av.x;
      As[akq * 4 + 1][ar] = av.y;
      As[akq * 4 + 2][ar] = av.z;
      As[akq * 4 + 3][ar] = av.w;
    }
#pragma unroll
    for (int i = 0; i < 2; ++i) {
      int v = tid + i * 256;
      int kk = v >> 5;
      int cq = v & 31;
      *reinterpret_cast<float4*>(&Bs[kk][cq * 4]) =
          *reinterpret_cast<const float4*>(&Bv[(k0 + kk) * OO + cq * 4]);
    }
    __syncthreads();
#pragma unroll
    for (int kk = 0; kk < 16; ++kk) {
      float4 b = *reinterpret_cast<const float4*>(&Bs[kk][tx * 4]);
#pragma unroll
      for (int r = 0; r < 8; ++r) {
        float a = As[kk][ty * 8 + r];
        acc[r][0] += a * b.x;
        acc[r][1] += a * b.y;
        acc[r][2] += a * b.z;
        acc[r][3] += a * b.w;
      }
    }
    __syncthreads();
  }
#pragma unroll
  for (int r = 0; r < 8; ++r) {
    int row = bm0 + ty * 8 + r;
    if (row < NN) {
      float4* cp = reinterpret_cast<float4*>(&C[(size_t)row * OO + tx * 4]);
      float4 c = *cp;
      c.x += acc[r][0];
      c.y += acc[r][1];
      c.z += acc[r][2];
      c.w += acc[r][3];
      *cp = c;
    }
  }
}

__global__ __launch_bounds__(256) void tanh_kernel(float* __restrict__ out) {
  int i = blockIdx.x * blockDim.x + threadIdx.x;
  float4* p = reinterpret_cast<float4*>(out) + i;
  float4 v = *p;
  v.x = tanhf(v.x);
  v.y = tanhf(v.y);
  v.z = tanhf(v.z);
  v.w = tanhf(v.w);
  *p = v;
}

// ===========================================================================
extern "C" void kernel_launch(void* const* d_in, const int* in_sizes, int n_in,
                              void* d_out, int out_size, void* d_ws,
                              size_t ws_size, hipStream_t stream) {
  const float* feat = (const float*)d_in[0];   // [N, F]
  const float* W = (const float*)d_in[1];      // [B, F, O]
  const float* Wc = (const float*)d_in[2];     // [S, B]
  const int* erows = (const int*)d_in[3];      // [S, E]
  const int* ecols = (const int*)d_in[4];      // [S, E]
  const float* evals = (const float*)d_in[5];  // [S, E]
  float* out = (float*)d_out;                  // [N, O] f32

  unsigned char* ws = (unsigned char*)d_ws;
  unsigned int* rs = (unsigned int*)ws;                // NN counts->starts->ends
  size_t recs_off = (((size_t)NN * 4) + 255) & ~(size_t)255;
  uintx2* recs = (uintx2*)(ws + recs_off);             // TOTE * 8B = 102.4MB
  size_t featb_off = recs_off + (size_t)TOTE * 8;
  unsigned int* featb = (unsigned int*)(ws + featb_off);  // 25.6MB
  size_t needed_f32 = featb_off;
  size_t needed_f16 = featb_off + (size_t)NN * FF * 2;

  if (ws_size >= needed_f32) {
    hipMemsetAsync(rs, 0, (size_t)NN * 4, stream);
    hist_row_kernel<<<512, 256, 0, stream>>>(erows, rs);
    scan_row_kernel<<<1, 1024, 0, stream>>>(rs);
    reorder_row_kernel<<<512, 256, 0, stream>>>(erows, ecols, evals, rs, recs);
    if (ws_size >= needed_f16) {
      cast_kernel<<<(NN * FF / 2) / 256, 256, 0, stream>>>(feat, featb);
      pull_fused_kernel<1><<<NN / 16, 256, 0, stream>>>(feat, featb, W, Wc,
                                                        recs, rs, out);
    } else {
      pull_fused_kernel<0><<<NN / 16, 256, 0, stream>>>(feat, featb, W, Wc,
                                                        recs, rs, out);
    }
  } else {
    float* V = (float*)d_ws;
    float* agg = V + (size_t)SS * FF * OO;
    compute_V_kernel<<<(SS * FF * OO) / 256, 256, 0, stream>>>(W, Wc, V);
    hipMemsetAsync(out, 0, (size_t)NN * OO * sizeof(float), stream);
    for (int s = 0; s < SS; ++s) {
      hipMemsetAsync(agg, 0, (size_t)NN * FF * sizeof(float), stream);
      scatter_kernel<<<(EE * 32) / 256, 256, 0, stream>>>(
          feat, erows + (size_t)s * EE, ecols + (size_t)s * EE,
          evals + (size_t)s * EE, agg);
      gemm_acc_kernel<<<(NN + 63) / 64, 256, 0, stream>>>(
          agg, V + (size_t)s * FF * OO, out);
    }
    tanh_kernel<<<(NN * OO / 4) / 256, 256, 0, stream>>>(out);
  }
}

// Round 12
// 1343.805 us; speedup vs baseline: 6.7050x; 1.7749x over previous
//
#include <hip/hip_runtime.h>
#include <hip/hip_bf16.h>
#include <hip/hip_fp16.h>

// Problem constants: N=100000, F=128, O=128, S=4, B=2, E=3200000
#define NN 100000
#define FF 128
#define OO 128
#define SS 4
#define BBASES 2
#define EE 3200000
#define TOTE (SS * EE)   // 12.8M edges total
#define BROWS 32         // rows per bucket
#define BSHIFT 5
#define NBUK 3125        // 100000/32 exactly
#define SCAP 5120        // LDS stage cap; lambda=4096, +16 sigma
#define RBLOCKS 512

typedef unsigned int uintx2 __attribute__((ext_vector_type(2)));
typedef float floatx4 __attribute__((ext_vector_type(4)));

// ===========================================================================
// out[n] = tanh( G0[n] @ W0 + G1[n] @ W1 ),
//   G_b[n] = sum_s Wc[s,b] * sum_{e in s: row_e=n} val_e * feat[col_e]
// R12: two-level counting sort (bucket partition + per-bucket LDS sort)
// kills the 8x write-amp of direct row scatter; then R11's proven pull
// kernel (dense register-accumulate gather, no atomics/readlane).
// Record: bits[16:0]=col, [18:17]=support, [23:19]=row-in-bucket.
// ===========================================================================

// ---- bucket histogram (LDS-staged) ----------------------------------------
__global__ __launch_bounds__(256) void histB_kernel(
    const int* __restrict__ rows, unsigned int* __restrict__ bhist) {
  __shared__ unsigned int lh[NBUK];
  for (int i = threadIdx.x; i < NBUK; i += 256) lh[i] = 0;
  __syncthreads();
  const int stride = gridDim.x * 256;
  for (int i = blockIdx.x * 256 + threadIdx.x; i < TOTE; i += stride)
    atomicAdd(&lh[((unsigned)rows[i]) >> BSHIFT], 1u);
  __syncthreads();
  for (int i = threadIdx.x; i < NBUK; i += 256) {
    unsigned int c = lh[i];
    if (c) atomicAdd(&bhist[i], c);
  }
}

// ---- exclusive scan over NBUK buckets (single block) ----------------------
__global__ __launch_bounds__(256) void scanB_kernel(
    const unsigned int* __restrict__ bhist, unsigned int* __restrict__ bstart,
    unsigned int* __restrict__ cursor) {
  __shared__ unsigned int sums[256];
  const int C = (NBUK + 255) / 256;  // 14
  const int t = threadIdx.x;
  unsigned int s = 0;
  for (int j = 0; j < C; ++j) {
    int i = t * C + j;
    if (i < NBUK) s += bhist[i];
  }
  sums[t] = s;
  __syncthreads();
  for (int off = 1; off < 256; off <<= 1) {
    unsigned int v = (t >= off) ? sums[t - off] : 0u;
    __syncthreads();
    sums[t] += v;
    __syncthreads();
  }
  unsigned int base = (t == 0) ? 0u : sums[t - 1];
  for (int j = 0; j < C; ++j) {
    int i = t * C + j;
    if (i < NBUK) {
      unsigned int h = bhist[i];
      bstart[i] = base;
      cursor[i] = base;
      base += h;
    }
  }
  if (t == 255) bstart[NBUK] = base;  // == TOTE
}

// ---- partition edges into buckets (block-chunked reservations) ------------
__global__ __launch_bounds__(256) void partition_kernel(
    const int* __restrict__ rows, const int* __restrict__ cols,
    const float* __restrict__ vals, unsigned int* __restrict__ cursor,
    uintx2* __restrict__ recs) {
  __shared__ unsigned int lcnt[NBUK];
  __shared__ unsigned int lbase[NBUK];
  const int C = (TOTE + RBLOCKS - 1) / RBLOCKS;  // 25000
  const int start = blockIdx.x * C;
  const int end = min(start + C, TOTE);
  for (int i = threadIdx.x; i < NBUK; i += 256) lcnt[i] = 0;
  __syncthreads();
  for (int i = start + threadIdx.x; i < end; i += 256)
    atomicAdd(&lcnt[((unsigned)rows[i]) >> BSHIFT], 1u);
  __syncthreads();
  for (int i = threadIdx.x; i < NBUK; i += 256) {
    unsigned int c = lcnt[i];
    if (c) lbase[i] = atomicAdd(&cursor[i], c);
    lcnt[i] = 0;
  }
  __syncthreads();
  for (int i = start + threadIdx.x; i < end; i += 256) {
    unsigned int r = (unsigned)rows[i];
    int bk = r >> BSHIFT;
    unsigned int p = lbase[bk] + atomicAdd(&lcnt[bk], 1u);
    unsigned int s = (unsigned)(i / EE);
    uintx2 rec;
    rec.x = ((unsigned)cols[i]) | (s << 17) | ((r & (BROWS - 1u)) << 19);
    rec.y = __float_as_uint(vals[i]);
    __builtin_nontemporal_store(rec, &recs[p]);
  }
}

// ---- per-bucket LDS counting sort by row + rs(row-end) emission -----------
__global__ __launch_bounds__(256) void bsort_kernel(
    const unsigned int* __restrict__ bstart, uintx2* __restrict__ recs,
    unsigned int* __restrict__ rs) {
  __shared__ uintx2 buf[SCAP];              // 40 KB
  __shared__ unsigned int h[BROWS], st[BROWS], cur[BROWS];
  const int b = blockIdx.x;
  const unsigned int e0 = bstart[b];
  const int len = (int)(bstart[b + 1] - e0);  // <= SCAP (16-sigma bound)
  const int tid = threadIdx.x;
  if (tid < BROWS) h[tid] = 0;
  __syncthreads();
  for (int i = tid; i < len; i += 256) {
    uintx2 r = __builtin_nontemporal_load(&recs[e0 + i]);
    buf[i] = r;
    atomicAdd(&h[r.x >> 19], 1u);
  }
  __syncthreads();
  if (tid == 0) {
    unsigned int run = 0;
#pragma unroll
    for (int j = 0; j < BROWS; ++j) {
      st[j] = run;
      cur[j] = run;
      run += h[j];
    }
  }
  __syncthreads();
  if (tid < BROWS) rs[b * BROWS + tid] = e0 + st[tid] + h[tid];  // row END
  for (int i = tid; i < len; i += 256) {
    uintx2 r = buf[i];
    unsigned int j = r.x >> 19;
    unsigned int pos = atomicAdd(&cur[j], 1u);
    recs[e0 + pos] = r;  // random within 40KB block-owned region: L2-merged
  }
}

// ---- fp16 cast of feat: fb[i] packs elements 2i,2i+1 as half2 (RNE) -------
__global__ __launch_bounds__(256) void cast_kernel(const float* __restrict__ f,
                                                   unsigned int* __restrict__ fb) {
  int i = blockIdx.x * 256 + threadIdx.x;  // over N*F/2 = 6.4M pairs
  float2 a = reinterpret_cast<const float2*>(f)[i];
  __half2 h = __floats2half2_rn(a.x, a.y);
  fb[i] = *reinterpret_cast<unsigned int*>(&h);
}

// ---- pull + fused GEMM + tanh (R11-proven) --------------------------------
template <int MODE>
__global__ __launch_bounds__(256, 6) void pull_fused_kernel(
    const float* __restrict__ feat, const unsigned int* __restrict__ featb,
    const float* __restrict__ W, const float* __restrict__ Wc,
    const uintx2* __restrict__ recs, const unsigned int* __restrict__ rs,
    float* __restrict__ out) {
  __shared__ float G[16][2 * FF];  // 16 KB
  const int tid = threadIdx.x;
  const int nl = tid >> 4;  // 0..15 row within block
  const int q = tid & 15;   // feature chunk: elems 8q..8q+7
  const int n = blockIdx.x * 16 + nl;

  const unsigned int e1 = rs[n];
  const unsigned int e0 = (n == 0) ? 0u : rs[n - 1];

  const float c00 = Wc[0], c01 = Wc[1], c10 = Wc[2], c11 = Wc[3];
  const float c20 = Wc[4], c21 = Wc[5], c30 = Wc[6], c31 = Wc[7];

  float a0[8], a1[8];
#pragma unroll
  for (int k = 0; k < 8; ++k) {
    a0[k] = 0.f;
    a1[k] = 0.f;
  }

  for (unsigned int e = e0; e < e1; ++e) {
    uintx2 rec = recs[e];  // 8B, shared by this row's 16 threads (broadcast)
    unsigned int c = rec.x & 0x1FFFFu;
    unsigned int s = (rec.x >> 17) & 3u;  // mask: bits 19+ hold rowLocal now
    float v = __uint_as_float(rec.y);
    float w0 = (s == 0) ? c00 : (s == 1) ? c10 : (s == 2) ? c20 : c30;
    float w1 = (s == 0) ? c01 : (s == 1) ? c11 : (s == 2) ? c21 : c31;
    float v0 = v * w0, v1 = v * w1;
    if constexpr (MODE == 1) {
      uint4 xv = *reinterpret_cast<const uint4*>(&featb[((size_t)c << 6) + (q << 2)]);
      const __half2* hp = reinterpret_cast<const __half2*>(&xv);
#pragma unroll
      for (int h = 0; h < 4; ++h) {
        float2 f = __half22float2(hp[h]);
        a0[2 * h] += v0 * f.x;
        a0[2 * h + 1] += v0 * f.y;
        a1[2 * h] += v1 * f.x;
        a1[2 * h + 1] += v1 * f.y;
      }
    } else {
      float4 xa = *reinterpret_cast<const float4*>(&feat[((size_t)c << 7) + (q << 3)]);
      float4 xb = *reinterpret_cast<const float4*>(&feat[((size_t)c << 7) + (q << 3) + 4]);
      a0[0] += v0 * xa.x; a0[1] += v0 * xa.y; a0[2] += v0 * xa.z; a0[3] += v0 * xa.w;
      a0[4] += v0 * xb.x; a0[5] += v0 * xb.y; a0[6] += v0 * xb.z; a0[7] += v0 * xb.w;
      a1[0] += v1 * xa.x; a1[1] += v1 * xa.y; a1[2] += v1 * xa.z; a1[3] += v1 * xa.w;
      a1[4] += v1 * xb.x; a1[5] += v1 * xb.y; a1[6] += v1 * xb.z; a1[7] += v1 * xb.w;
    }
  }

#pragma unroll
  for (int k = 0; k < 8; ++k) {
    G[nl][q * 8 + k] = a0[k];
    G[nl][FF + q * 8 + k] = a1[k];
  }
  __syncthreads();

  // GEMM epilogue: out[row][o] = tanh(sum_{k<256} G[r][k] * Wcat[k][o])
  const int tx = tid & 31;
  const int ty = tid >> 5;
  float acc[2][4];
#pragma unroll
  for (int r = 0; r < 2; ++r)
#pragma unroll
    for (int c = 0; c < 4; ++c) acc[r][c] = 0.f;

  for (int k = 0; k < 2 * FF; ++k) {
    float4 bv = *reinterpret_cast<const float4*>(&W[k * OO + tx * 4]);
#pragma unroll
    for (int r = 0; r < 2; ++r) {
      float a = G[ty * 2 + r][k];
      acc[r][0] += a * bv.x;
      acc[r][1] += a * bv.y;
      acc[r][2] += a * bv.z;
      acc[r][3] += a * bv.w;
    }
  }
#pragma unroll
  for (int r = 0; r < 2; ++r) {
    int row = blockIdx.x * 16 + ty * 2 + r;
    floatx4 o;
    o.x = tanhf(acc[r][0]);
    o.y = tanhf(acc[r][1]);
    o.z = tanhf(acc[r][2]);
    o.w = tanhf(acc[r][3]);
    __builtin_nontemporal_store(o, (floatx4*)&out[(size_t)row * OO + tx * 4]);
  }
}

// ===========================================================================
// FALLBACK PATH (round-1, proven): used only if ws_size is too small
// ===========================================================================
__global__ void compute_V_kernel(const float* __restrict__ W,
                                 const float* __restrict__ Wc,
                                 float* __restrict__ V) {
  int i = blockIdx.x * blockDim.x + threadIdx.x;
  int s = i >> 14;
  int fo = i & 16383;
  V[i] = Wc[s * BBASES + 0] * W[fo] + Wc[s * BBASES + 1] * W[16384 + fo];
}

__global__ __launch_bounds__(256) void scatter_kernel(
    const float* __restrict__ feat, const int* __restrict__ rows,
    const int* __restrict__ cols, const float* __restrict__ vals,
    float* __restrict__ agg) {
  int t = blockIdx.x * blockDim.x + threadIdx.x;
  int e = t >> 5;
  int qq = t & 31;
  if (e >= EE) return;
  int r = rows[e];
  int c = cols[e];
  float v = vals[e];
  const float4 x = *reinterpret_cast<const float4*>(&feat[(size_t)c * FF + qq * 4]);
  float* dst = &agg[(size_t)r * FF + qq * 4];
  unsafeAtomicAdd(dst + 0, v * x.x);
  unsafeAtomicAdd(dst + 1, v * x.y);
  unsafeAtomicAdd(dst + 2, v * x.z);
  unsafeAtomicAdd(dst + 3, v * x.w);
}

__global__ __launch_bounds__(256) void gemm_acc_kernel(
    const float* __restrict__ A, const float* __restrict__ Bv,
    float* __restrict__ C) {
  __shared__ float As[16][64];
  __shared__ float Bs[16][128];
  const int tid = threadIdx.x;
  const int bm0 = blockIdx.x * 64;
  const int tx = tid & 31;
  const int ty = tid >> 5;
  float acc[8][4];
#pragma unroll
  for (int r = 0; r < 8; ++r)
#pragma unroll
    for (int c = 0; c < 4; ++c) acc[r][c] = 0.0f;
  const int ar = tid >> 2;
  const int akq = tid & 3;
  for (int k0 = 0; k0 < FF; k0 += 16) {
    {
      int row = bm0 + ar;
      float4 av = make_float4(0.f, 0.f, 0.f, 0.f);
      if (row < NN)
        av = *reinterpret_cast<const float4*>(&A[(size_t)row * FF + k0 + akq * 4]);
      As[akq * 4 + 0][ar] = av.x;
      As[akq * 4 + 1][ar] = av.y;
      As[akq * 4 + 2][ar] = av.z;
      As[akq * 4 + 3][ar] = av.w;
    }
#pragma unroll
    for (int i = 0; i < 2; ++i) {
      int v = tid + i * 256;
      int kk = v >> 5;
      int cq = v & 31;
      *reinterpret_cast<float4*>(&Bs[kk][cq * 4]) =
          *reinterpret_cast<const float4*>(&Bv[(k0 + kk) * OO + cq * 4]);
    }
    __syncthreads();
#pragma unroll
    for (int kk = 0; kk < 16; ++kk) {
      float4 b = *reinterpret_cast<const float4*>(&Bs[kk][tx * 4]);
#pragma unroll
      for (int r = 0; r < 8; ++r) {
        float a = As[kk][ty * 8 + r];
        acc[r][0] += a * b.x;
        acc[r][1] += a * b.y;
        acc[r][2] += a * b.z;
        acc[r][3] += a * b.w;
      }
    }
    __syncthreads();
  }
#pragma unroll
  for (int r = 0; r < 8; ++r) {
    int row = bm0 + ty * 8 + r;
    if (row < NN) {
      float4* cp = reinterpret_cast<float4*>(&C[(size_t)row * OO + tx * 4]);
      float4 c = *cp;
      c.x += acc[r][0];
      c.y += acc[r][1];
      c.z += acc[r][2];
      c.w += acc[r][3];
      *cp = c;
    }
  }
}

__global__ __launch_bounds__(256) void tanh_kernel(float* __restrict__ out) {
  int i = blockIdx.x * blockDim.x + threadIdx.x;
  float4* p = reinterpret_cast<float4*>(out) + i;
  float4 v = *p;
  v.x = tanhf(v.x);
  v.y = tanhf(v.y);
  v.z = tanhf(v.z);
  v.w = tanhf(v.w);
  *p = v;
}

// ===========================================================================
extern "C" void kernel_launch(void* const* d_in, const int* in_sizes, int n_in,
                              void* d_out, int out_size, void* d_ws,
                              size_t ws_size, hipStream_t stream) {
  const float* feat = (const float*)d_in[0];   // [N, F]
  const float* W = (const float*)d_in[1];      // [B, F, O]
  const float* Wc = (const float*)d_in[2];     // [S, B]
  const int* erows = (const int*)d_in[3];      // [S, E]
  const int* ecols = (const int*)d_in[4];      // [S, E]
  const float* evals = (const float*)d_in[5];  // [S, E]
  float* out = (float*)d_out;                  // [N, O] f32

  unsigned char* ws = (unsigned char*)d_ws;
  unsigned int* rs = (unsigned int*)ws;  // NN row-ends
  size_t off = (((size_t)NN * 4) + 255) & ~(size_t)255;
  unsigned int* bhist = (unsigned int*)(ws + off);
  off += (((size_t)NBUK * 4) + 255) & ~(size_t)255;
  unsigned int* bstart = (unsigned int*)(ws + off);
  off += (((size_t)(NBUK + 1) * 4) + 255) & ~(size_t)255;
  unsigned int* cursor = (unsigned int*)(ws + off);
  off += (((size_t)NBUK * 4) + 255) & ~(size_t)255;
  uintx2* recs = (uintx2*)(ws + off);  // TOTE*8 = 102.4MB
  off += (size_t)TOTE * 8;
  unsigned int* featb = (unsigned int*)(ws + off);  // 25.6MB
  size_t needed_f32 = off;
  size_t needed_f16 = off + (size_t)NN * FF * 2;

  if (ws_size >= needed_f32) {
    hipMemsetAsync(bhist, 0, (size_t)NBUK * 4, stream);
    histB_kernel<<<RBLOCKS, 256, 0, stream>>>(erows, bhist);
    scanB_kernel<<<1, 256, 0, stream>>>(bhist, bstart, cursor);
    partition_kernel<<<RBLOCKS, 256, 0, stream>>>(erows, ecols, evals, cursor, recs);
    bsort_kernel<<<NBUK, 256, 0, stream>>>(bstart, recs, rs);
    if (ws_size >= needed_f16) {
      cast_kernel<<<(NN * FF / 2) / 256, 256, 0, stream>>>(feat, featb);
      pull_fused_kernel<1><<<NN / 16, 256, 0, stream>>>(feat, featb, W, Wc,
                                                        recs, rs, out);
    } else {
      pull_fused_kernel<0><<<NN / 16, 256, 0, stream>>>(feat, featb, W, Wc,
                                                        recs, rs, out);
    }
  } else {
    float* V = (float*)d_ws;
    float* agg = V + (size_t)SS * FF * OO;
    compute_V_kernel<<<(SS * FF * OO) / 256, 256, 0, stream>>>(W, Wc, V);
    hipMemsetAsync(out, 0, (size_t)NN * OO * sizeof(float), stream);
    for (int s = 0; s < SS; ++s) {
      hipMemsetAsync(agg, 0, (size_t)NN * FF * sizeof(float), stream);
      scatter_kernel<<<(EE * 32) / 256, 256, 0, stream>>>(
          feat, erows + (size_t)s * EE, ecols + (size_t)s * EE,
          evals + (size_t)s * EE, agg);
      gemm_acc_kernel<<<(NN + 63) / 64, 256, 0, stream>>>(
          agg, V + (size_t)s * FF * OO, out);
    }
    tanh_kernel<<<(NN * OO / 4) / 256, 256, 0, stream>>>(out);
  }
}

// Round 14
// 1132.400 us; speedup vs baseline: 7.9568x; 1.1867x over previous
//
#include <hip/hip_runtime.h>
#include <hip/hip_bf16.h>
#include <hip/hip_fp16.h>

// Problem constants: N=100000, F=128, O=128, S=4, B=2, E=3200000
#define NN 100000
#define FF 128
#define OO 128
#define SS 4
#define BBASES 2
#define EE 3200000
#define TOTE (SS * EE)   // 12.8M edges total
#define BROWS 32         // rows per bucket
#define BSHIFT 5
#define NBUK 3125        // 100000/32 exactly
#define SCAP 5120        // LDS stage cap; lambda=4096, +16 sigma
#define RBLOCKS 512

typedef unsigned int uintx2 __attribute__((ext_vector_type(2)));
typedef float floatx4 __attribute__((ext_vector_type(4)));

static __device__ __forceinline__ float2 h2_to_f2(unsigned int u) {
  __half2 h = *reinterpret_cast<__half2*>(&u);
  return __half22float2(h);
}

// ===========================================================================
// out[n] = tanh( G0[n] @ W0 + G1[n] @ W1 ),
//   G_b[n] = sum_{edges e->n} (val_e * Wc[s_e,b]) * feat[col_e]
// R14 (= R13 + compile fix): Wc folded into the record at partition time
// (rec.y = half2(v0,v1)); bsort fused into the pull kernel: block = 1 bucket
// (32 rows, 512 thr), records register-staged + LDS counting-sorted, pull
// reads recs from LDS, epilogue GEMM reuses the same LDS for G[32][256].
// Record: bits[16:0]=col, [21:17]=row-in-bucket. rec.y = half2(v0,v1).
// ===========================================================================

// ---- bucket histogram (LDS-staged) ----------------------------------------
__global__ __launch_bounds__(256) void histB_kernel(
    const int* __restrict__ rows, unsigned int* __restrict__ bhist) {
  __shared__ unsigned int lh[NBUK];
  for (int i = threadIdx.x; i < NBUK; i += 256) lh[i] = 0;
  __syncthreads();
  const int stride = gridDim.x * 256;
  for (int i = blockIdx.x * 256 + threadIdx.x; i < TOTE; i += stride)
    atomicAdd(&lh[((unsigned)rows[i]) >> BSHIFT], 1u);
  __syncthreads();
  for (int i = threadIdx.x; i < NBUK; i += 256) {
    unsigned int c = lh[i];
    if (c) atomicAdd(&bhist[i], c);
  }
}

// ---- exclusive scan over NBUK buckets (single block) ----------------------
__global__ __launch_bounds__(256) void scanB_kernel(
    const unsigned int* __restrict__ bhist, unsigned int* __restrict__ bstart,
    unsigned int* __restrict__ cursor) {
  __shared__ unsigned int sums[256];
  const int C = (NBUK + 255) / 256;  // 14
  const int t = threadIdx.x;
  unsigned int s = 0;
  for (int j = 0; j < C; ++j) {
    int i = t * C + j;
    if (i < NBUK) s += bhist[i];
  }
  sums[t] = s;
  __syncthreads();
  for (int off = 1; off < 256; off <<= 1) {
    unsigned int v = (t >= off) ? sums[t - off] : 0u;
    __syncthreads();
    sums[t] += v;
    __syncthreads();
  }
  unsigned int base = (t == 0) ? 0u : sums[t - 1];
  for (int j = 0; j < C; ++j) {
    int i = t * C + j;
    if (i < NBUK) {
      unsigned int h = bhist[i];
      bstart[i] = base;
      cursor[i] = base;
      base += h;
    }
  }
  if (t == 255) bstart[NBUK] = base;  // == TOTE
}

// ---- partition edges into buckets; fold Wc into the value -----------------
__global__ __launch_bounds__(256) void partition_kernel(
    const int* __restrict__ rows, const int* __restrict__ cols,
    const float* __restrict__ vals, const float* __restrict__ Wc,
    unsigned int* __restrict__ cursor, uintx2* __restrict__ recs) {
  __shared__ unsigned int lcnt[NBUK];
  __shared__ unsigned int lbase[NBUK];
  const float c00 = Wc[0], c01 = Wc[1], c10 = Wc[2], c11 = Wc[3];
  const float c20 = Wc[4], c21 = Wc[5], c30 = Wc[6], c31 = Wc[7];
  const int C = (TOTE + RBLOCKS - 1) / RBLOCKS;  // 25000
  const int start = blockIdx.x * C;
  const int end = min(start + C, TOTE);
  for (int i = threadIdx.x; i < NBUK; i += 256) lcnt[i] = 0;
  __syncthreads();
  for (int i = start + threadIdx.x; i < end; i += 256)
    atomicAdd(&lcnt[((unsigned)rows[i]) >> BSHIFT], 1u);
  __syncthreads();
  for (int i = threadIdx.x; i < NBUK; i += 256) {
    unsigned int c = lcnt[i];
    if (c) lbase[i] = atomicAdd(&cursor[i], c);
    lcnt[i] = 0;
  }
  __syncthreads();
  for (int i = start + threadIdx.x; i < end; i += 256) {
    unsigned int r = (unsigned)rows[i];
    int bk = r >> BSHIFT;
    unsigned int p = lbase[bk] + atomicAdd(&lcnt[bk], 1u);
    unsigned int s = (unsigned)(i / EE);
    float val = vals[i];
    float w0 = (s == 0) ? c00 : (s == 1) ? c10 : (s == 2) ? c20 : c30;
    float w1 = (s == 0) ? c01 : (s == 1) ? c11 : (s == 2) ? c21 : c31;
    __half2 hv = __floats2half2_rn(val * w0, val * w1);
    uintx2 rec;
    rec.x = ((unsigned)cols[i]) | ((r & (BROWS - 1u)) << 17);
    rec.y = *reinterpret_cast<unsigned int*>(&hv);
    __builtin_nontemporal_store(rec, &recs[p]);
  }
}

// ---- fp16 cast of feat: fb[i] packs elements 2i,2i+1 as half2 (RNE) -------
__global__ __launch_bounds__(256) void cast_kernel(const float* __restrict__ f,
                                                   unsigned int* __restrict__ fb) {
  int i = blockIdx.x * 256 + threadIdx.x;  // over N*F/2 = 6.4M pairs
  float2 a = reinterpret_cast<const float2*>(f)[i];
  __half2 h = __floats2half2_rn(a.x, a.y);
  fb[i] = *reinterpret_cast<unsigned int*>(&h);
}

// ---- fused: in-block sort + register pull + GEMM + tanh -------------------
// Block = 1 bucket = 32 rows, 512 threads (16/row; thread q owns elems
// 8q..8q+7). LDS buf (sorted recs, 40KB) aliased with epilogue G[32][256].
#define LITERS ((SCAP + 511) / 512)  // 10
__global__ __launch_bounds__(512, 8) void pullsort_fused_kernel(
    const unsigned int* __restrict__ featb, const float* __restrict__ W,
    const uintx2* __restrict__ recs, const unsigned int* __restrict__ bstart,
    float* __restrict__ out) {
  __shared__ __align__(16) unsigned char smem[SCAP * 8];  // 40 KB
  __shared__ unsigned int h[BROWS], st[BROWS], cur[BROWS];
  uintx2* buf = (uintx2*)smem;
  float* G = (float*)smem;  // aliased: epilogue uses 32 KB of it
  const int tid = threadIdx.x;
  const int b = blockIdx.x;
  const unsigned int e0 = bstart[b];
  const unsigned int e1b = bstart[b + 1];
  const int len = (int)(e1b - e0);
  const bool fits = (len <= SCAP);

  if (tid < BROWS) h[tid] = 0;
  __syncthreads();

  // pass 1: register-stage records + LDS histogram (statically indexed)
  uintx2 loc[LITERS];
  if (fits) {
#pragma unroll
    for (int it = 0; it < LITERS; ++it) {
      int i = tid + it * 512;
      if (i < len) {
        uintx2 r = __builtin_nontemporal_load(&recs[e0 + i]);
        loc[it] = r;
        atomicAdd(&h[r.x >> 17], 1u);
      }
    }
  }
  __syncthreads();
  if (tid == 0) {
    unsigned int run = 0;
#pragma unroll
    for (int j = 0; j < BROWS; ++j) {
      st[j] = run;
      cur[j] = run;
      run += h[j];
    }
  }
  __syncthreads();
  // pass 2: scatter registers -> LDS sorted positions
  if (fits) {
#pragma unroll
    for (int it = 0; it < LITERS; ++it) {
      int i = tid + it * 512;
      if (i < len) {
        uintx2 r = loc[it];
        unsigned int pos = atomicAdd(&cur[r.x >> 17], 1u);
        buf[pos] = r;
      }
    }
  }
  __syncthreads();

  // pull phase: row nl = tid>>4, feature chunk q = tid&15 (elems 8q..8q+7)
  const int nl = tid >> 4;
  const int q = tid & 15;
  float a0[8], a1[8];
#pragma unroll
  for (int k = 0; k < 8; ++k) {
    a0[k] = 0.f;
    a1[k] = 0.f;
  }

  if (fits) {
    const unsigned int rbeg = st[nl];
    const unsigned int rend = rbeg + h[nl];
    for (unsigned int e = rbeg; e < rend; ++e) {
      uintx2 rec = buf[e];  // LDS broadcast across the 16 row-threads
      unsigned int c = rec.x & 0x1FFFFu;
      float2 vv = h2_to_f2(rec.y);
      uint4 xv = *reinterpret_cast<const uint4*>(&featb[(c << 6) + (q << 2)]);
      const __half2* hp = reinterpret_cast<const __half2*>(&xv);
#pragma unroll
      for (int m = 0; m < 4; ++m) {
        float2 f = __half22float2(hp[m]);
        a0[2 * m] += vv.x * f.x;
        a0[2 * m + 1] += vv.x * f.y;
        a1[2 * m] += vv.y * f.x;
        a1[2 * m + 1] += vv.y * f.y;
      }
    }
  } else {
    // overflow fallback (statistically never): filter-scan global records
    for (unsigned int e = e0; e < e1b; ++e) {
      uintx2 rec = recs[e];
      if ((int)(rec.x >> 17) == nl) {
        unsigned int c = rec.x & 0x1FFFFu;
        float2 vv = h2_to_f2(rec.y);
        uint4 xv = *reinterpret_cast<const uint4*>(&featb[(c << 6) + (q << 2)]);
        const __half2* hp = reinterpret_cast<const __half2*>(&xv);
#pragma unroll
        for (int m = 0; m < 4; ++m) {
          float2 f = __half22float2(hp[m]);
          a0[2 * m] += vv.x * f.x;
          a0[2 * m + 1] += vv.x * f.y;
          a1[2 * m] += vv.y * f.x;
          a1[2 * m + 1] += vv.y * f.y;
        }
      }
    }
  }
  __syncthreads();  // all buf reads done before G overwrites it (alias)

#pragma unroll
  for (int k = 0; k < 8; ++k) {
    G[nl * 256 + q * 8 + k] = a0[k];
    G[nl * 256 + FF + q * 8 + k] = a1[k];
  }
  __syncthreads();

  // GEMM epilogue: out[row][o] = tanh(sum_{k<256} G[r][k] * Wcat[k][o])
  // W is [B][F][O] contiguous = stacked [256][128]; G row = [G0 | G1].
  const int tx = tid & 31;  // cols tx*4..tx*4+3
  const int ty = tid >> 5;  // 0..15 -> rows 2ty, 2ty+1
  float acc[2][4];
#pragma unroll
  for (int r = 0; r < 2; ++r)
#pragma unroll
    for (int c = 0; c < 4; ++c) acc[r][c] = 0.f;

  for (int k = 0; k < 2 * FF; ++k) {
    float4 bv = *reinterpret_cast<const float4*>(&W[k * OO + tx * 4]);
#pragma unroll
    for (int r = 0; r < 2; ++r) {
      float a = G[(ty * 2 + r) * 256 + k];  // LDS broadcast per half-wave
      acc[r][0] += a * bv.x;
      acc[r][1] += a * bv.y;
      acc[r][2] += a * bv.z;
      acc[r][3] += a * bv.w;
    }
  }
#pragma unroll
  for (int r = 0; r < 2; ++r) {
    int row = b * BROWS + ty * 2 + r;  // N divisible by 32
    floatx4 o;
    o.x = tanhf(acc[r][0]);
    o.y = tanhf(acc[r][1]);
    o.z = tanhf(acc[r][2]);
    o.w = tanhf(acc[r][3]);
    __builtin_nontemporal_store(o, (floatx4*)&out[(size_t)row * OO + tx * 4]);
  }
}

// ===========================================================================
// FALLBACK PATH (round-1, proven): used only if ws_size is too small
// ===========================================================================
__global__ void compute_V_kernel(const float* __restrict__ W,
                                 const float* __restrict__ Wc,
                                 float* __restrict__ V) {
  int i = blockIdx.x * blockDim.x + threadIdx.x;
  int s = i >> 14;
  int fo = i & 16383;
  V[i] = Wc[s * BBASES + 0] * W[fo] + Wc[s * BBASES + 1] * W[16384 + fo];
}

__global__ __launch_bounds__(256) void scatter_kernel(
    const float* __restrict__ feat, const int* __restrict__ rows,
    const int* __restrict__ cols, const float* __restrict__ vals,
    float* __restrict__ agg) {
  int t = blockIdx.x * blockDim.x + threadIdx.x;
  int e = t >> 5;
  int qq = t & 31;
  if (e >= EE) return;
  int r = rows[e];
  int c = cols[e];
  float v = vals[e];
  const float4 x = *reinterpret_cast<const float4*>(&feat[(size_t)c * FF + qq * 4]);
  float* dst = &agg[(size_t)r * FF + qq * 4];
  unsafeAtomicAdd(dst + 0, v * x.x);
  unsafeAtomicAdd(dst + 1, v * x.y);
  unsafeAtomicAdd(dst + 2, v * x.z);
  unsafeAtomicAdd(dst + 3, v * x.w);
}

__global__ __launch_bounds__(256) void gemm_acc_kernel(
    const float* __restrict__ A, const float* __restrict__ Bv,
    float* __restrict__ C) {
  __shared__ float As[16][64];
  __shared__ float Bs[16][128];
  const int tid = threadIdx.x;
  const int bm0 = blockIdx.x * 64;
  const int tx = tid & 31;
  const int ty = tid >> 5;
  float acc[8][4];
#pragma unroll
  for (int r = 0; r < 8; ++r)
#pragma unroll
    for (int c = 0; c < 4; ++c) acc[r][c] = 0.0f;
  const int ar = tid >> 2;
  const int akq = tid & 3;
  for (int k0 = 0; k0 < FF; k0 += 16) {
    {
      int row = bm0 + ar;
      float4 av = make_float4(0.f, 0.f, 0.f, 0.f);
      if (row < NN)
        av = *reinterpret_cast<const float4*>(&A[(size_t)row * FF + k0 + akq * 4]);
      As[akq * 4 + 0][ar] = av.x;
      As[akq * 4 + 1][ar] = av.y;
      As[akq * 4 + 2][ar] = av.z;
      As[akq * 4 + 3][ar] = av.w;
    }
#pragma unroll
    for (int i = 0; i < 2; ++i) {
      int v = tid + i * 256;
      int kk = v >> 5;
      int cq = v & 31;
      *reinterpret_cast<float4*>(&Bs[kk][cq * 4]) =
          *reinterpret_cast<const float4*>(&Bv[(k0 + kk) * OO + cq * 4]);
    }
    __syncthreads();
#pragma unroll
    for (int kk = 0; kk < 16; ++kk) {
      float4 b = *reinterpret_cast<const float4*>(&Bs[kk][tx * 4]);
#pragma unroll
      for (int r = 0; r < 8; ++r) {
        float a = As[kk][ty * 8 + r];
        acc[r][0] += a * b.x;
        acc[r][1] += a * b.y;
        acc[r][2] += a * b.z;
        acc[r][3] += a * b.w;
      }
    }
    __syncthreads();
  }
#pragma unroll
  for (int r = 0; r < 8; ++r) {
    int row = bm0 + ty * 8 + r;
    if (row < NN) {
      float4* cp = reinterpret_cast<float4*>(&C[(size_t)row * OO + tx * 4]);
      float4 c = *cp;
      c.x += acc[r][0];
      c.y += acc[r][1];
      c.z += acc[r][2];
      c.w += acc[r][3];
      *cp = c;
    }
  }
}

__global__ __launch_bounds__(256) void tanh_kernel(float* __restrict__ out) {
  int i = blockIdx.x * blockDim.x + threadIdx.x;
  float4* p = reinterpret_cast<float4*>(out) + i;
  float4 v = *p;
  v.x = tanhf(v.x);
  v.y = tanhf(v.y);
  v.z = tanhf(v.z);
  v.w = tanhf(v.w);
  *p = v;
}

// ===========================================================================
extern "C" void kernel_launch(void* const* d_in, const int* in_sizes, int n_in,
                              void* d_out, int out_size, void* d_ws,
                              size_t ws_size, hipStream_t stream) {
  const float* feat = (const float*)d_in[0];   // [N, F]
  const float* W = (const float*)d_in[1];      // [B, F, O]
  const float* Wc = (const float*)d_in[2];     // [S, B]
  const int* erows = (const int*)d_in[3];      // [S, E]
  const int* ecols = (const int*)d_in[4];      // [S, E]
  const float* evals = (const float*)d_in[5];  // [S, E]
  float* out = (float*)d_out;                  // [N, O] f32

  unsigned char* ws = (unsigned char*)d_ws;
  size_t off = 0;
  unsigned int* bhist = (unsigned int*)(ws + off);
  off += (((size_t)NBUK * 4) + 255) & ~(size_t)255;
  unsigned int* bstart = (unsigned int*)(ws + off);
  off += (((size_t)(NBUK + 1) * 4) + 255) & ~(size_t)255;
  unsigned int* cursor = (unsigned int*)(ws + off);
  off += (((size_t)NBUK * 4) + 255) & ~(size_t)255;
  uintx2* recs = (uintx2*)(ws + off);  // TOTE*8 = 102.4MB
  off += (size_t)TOTE * 8;
  unsigned int* featb = (unsigned int*)(ws + off);  // 25.6MB
  size_t needed = off + (size_t)NN * FF * 2;

  if (ws_size >= needed) {
    hipMemsetAsync(bhist, 0, (size_t)NBUK * 4, stream);
    histB_kernel<<<RBLOCKS, 256, 0, stream>>>(erows, bhist);
    scanB_kernel<<<1, 256, 0, stream>>>(bhist, bstart, cursor);
    partition_kernel<<<RBLOCKS, 256, 0, stream>>>(erows, ecols, evals, Wc,
                                                  cursor, recs);
    cast_kernel<<<(NN * FF / 2) / 256, 256, 0, stream>>>(feat, featb);
    pullsort_fused_kernel<<<NBUK, 512, 0, stream>>>(featb, W, recs, bstart, out);
  } else {
    float* V = (float*)d_ws;
    float* agg = V + (size_t)SS * FF * OO;
    compute_V_kernel<<<(SS * FF * OO) / 256, 256, 0, stream>>>(W, Wc, V);
    hipMemsetAsync(out, 0, (size_t)NN * OO * sizeof(float), stream);
    for (int s = 0; s < SS; ++s) {
      hipMemsetAsync(agg, 0, (size_t)NN * FF * sizeof(float), stream);
      scatter_kernel<<<(EE * 32) / 256, 256, 0, stream>>>(
          feat, erows + (size_t)s * EE, ecols + (size_t)s * EE,
          evals + (size_t)s * EE, agg);
      gemm_acc_kernel<<<(NN + 63) / 64, 256, 0, stream>>>(
          agg, V + (size_t)s * FF * OO, out);
    }
    tanh_kernel<<<(NN * OO / 4) / 256, 256, 0, stream>>>(out);
  }
}